// Round 2
// baseline (308.163 us; speedup 1.0000x reference)
//
#include <hip/hip_runtime.h>

typedef __attribute__((ext_vector_type(8))) short short8;
typedef __attribute__((ext_vector_type(4))) float floatx4;

__device__ __forceinline__ unsigned short f2b(float f) {
    union { float f; unsigned int i; } v; v.f = f;
    unsigned int u = v.i;
    u += 0x7FFFu + ((u >> 16) & 1u);   // round-nearest-even; NaN impossible here
    return (unsigned short)(u >> 16);
}

#define NTILES 2048   // 262144 rows / 128 rows-per-tile
#define GRID   1024   // persistent: each block handles 2 tiles, W staged once

// Block: 4 waves x 32 rows = 128 rows per tile.
// MFMA operands swapped: A = W (LDS), B = X.
// => C layout: col = x-row (lane&15, lane-local), row = dout = n*16+q*4+r.
//    - per-row scalar epilogue once per g (not per (g,r)), no row-scalar shfl bcast
//    - stores are float4 (lane owns 4 consecutive douts)
// Bias lives in LDS; fragments are reloaded in the epilogue so the 32 VGPRs
// are not live across the load/MFMA phases (keeps us under the 3-waves/SIMD cap).
// W (128x128 fp32) staged as bf16 in LDS, row stride 136 shorts (272 B).
__global__ __launch_bounds__(256, 3) void mobius_linear_kernel(
    const float* __restrict__ X,
    const float* __restrict__ W,
    const float* __restrict__ Bias,
    float* __restrict__ Out)
{
    __shared__ unsigned short ldsW[128 * 136];
    __shared__ float ldsB[128];

    const int tid  = threadIdx.x;
    const int wave = tid >> 6;
    const int lane = tid & 63;
    const int q = lane >> 4;     // quad
    const int c = lane & 15;     // lane-local: x-row (B/C col) & W-row (A row)

    // ---- stage W into LDS as bf16 (once per block) ----
#pragma unroll
    for (int i = 0; i < 8; ++i) {
        int chunk = i * 256 + tid;          // 0..2047
        int row = chunk >> 4, cc = chunk & 15;
        const float* src = W + row * 128 + cc * 8;
        floatx4 w0 = *reinterpret_cast<const floatx4*>(src);
        floatx4 w1 = *reinterpret_cast<const floatx4*>(src + 4);
        short8 pk;
#pragma unroll
        for (int j = 0; j < 4; ++j) { pk[j] = (short)f2b(w0[j]); pk[4 + j] = (short)f2b(w1[j]); }
        *reinterpret_cast<short8*>(&ldsW[row * 136 + cc * 8]) = pk;
    }
    // ---- stage Bias into LDS (fp32, 512 B) ----
    if (tid < 32)
        *reinterpret_cast<floatx4*>(&ldsB[tid * 4]) =
            *reinterpret_cast<const floatx4*>(Bias + tid * 4);

    __syncthreads();   // the ONLY barrier: LDS is read-only from here on

    // ---- ||b||^2 (one-time; registers freed afterwards) ----
    float b2 = 0.f;
#pragma unroll
    for (int n = 0; n < 8; ++n) {
        floatx4 bv = *reinterpret_cast<const floatx4*>(&ldsB[n * 16 + q * 4]);
#pragma unroll
        for (int r = 0; r < 4; ++r) b2 = fmaf(bv[r], bv[r], b2);
    }
    b2 += __shfl_xor(b2, 16); b2 += __shfl_xor(b2, 32);

    for (int t = blockIdx.x; t < NTILES; t += gridDim.x) {
        const int rowbase = t * 128 + wave * 32;

        // ---- X fragments (B operand): nt-load fp32, ||x||^2 in fp32, pack bf16 ----
        short8 xfrag[2][4];
        float xn2[2] = {0.f, 0.f};
#pragma unroll
        for (int g = 0; g < 2; ++g) {
            const float* xrow = X + (size_t)(rowbase + g * 16 + c) * 128;
#pragma unroll
            for (int kc = 0; kc < 4; ++kc) {
                const floatx4* src = reinterpret_cast<const floatx4*>(xrow + kc * 32 + q * 8);
                floatx4 x0 = __builtin_nontemporal_load(src);
                floatx4 x1 = __builtin_nontemporal_load(src + 1);
                short8 pk;
#pragma unroll
                for (int j = 0; j < 4; ++j) {
                    xn2[g] = fmaf(x0[j], x0[j], xn2[g]);
                    xn2[g] = fmaf(x1[j], x1[j], xn2[g]);
                    pk[j] = (short)f2b(x0[j]); pk[4 + j] = (short)f2b(x1[j]);
                }
                xfrag[g][kc] = pk;
            }
        }
        // quads hold disjoint k-ranges of the same row; sum over q
        xn2[0] += __shfl_xor(xn2[0], 16); xn2[0] += __shfl_xor(xn2[0], 32);
        xn2[1] += __shfl_xor(xn2[1], 16); xn2[1] += __shfl_xor(xn2[1], 32);

        // ---- MFMA: D[dout][xrow] ; A = W (LDS), B = X ----
        floatx4 acc[2][8];
#pragma unroll
        for (int g = 0; g < 2; ++g)
#pragma unroll
            for (int n = 0; n < 8; ++n)
                acc[g][n] = (floatx4){0.f, 0.f, 0.f, 0.f};

#pragma unroll
        for (int kc = 0; kc < 4; ++kc) {
#pragma unroll
            for (int n = 0; n < 8; ++n) {
                short8 wf = *reinterpret_cast<const short8*>(
                    &ldsW[(n * 16 + c) * 136 + kc * 32 + q * 8]);
                acc[0][n] = __builtin_amdgcn_mfma_f32_16x16x32_bf16(wf, xfrag[0][kc], acc[0][n], 0, 0, 0);
                acc[1][n] = __builtin_amdgcn_mfma_f32_16x16x32_bf16(wf, xfrag[1][kc], acc[1][n], 0, 0, 0);
            }
        }

        // ---- fused epilogue: lane owns x-row (rowbase + g*16 + c),
        //      douts {n*16 + q*4 + r}. Bias fragments reloaded from LDS. ----
        floatx4 bfr[8];
#pragma unroll
        for (int n = 0; n < 8; ++n)
            bfr[n] = *reinterpret_cast<const floatx4*>(&ldsB[n * 16 + q * 4]);

#pragma unroll
        for (int g = 0; g < 2; ++g) {
            float m2 = 0.f, mbv = 0.f;
#pragma unroll
            for (int n = 0; n < 8; ++n)
#pragma unroll
                for (int r = 0; r < 4; ++r) {
                    float v = acc[g][n][r];
                    m2  = fmaf(v, v, m2);
                    mbv = fmaf(v, bfr[n][r], mbv);
                }
            // disjoint dout-sets across quads; sum over q
            m2  += __shfl_xor(m2, 16);  m2  += __shfl_xor(m2, 32);
            mbv += __shfl_xor(mbv, 16); mbv += __shfl_xor(mbv, 32);

            float xnorm = fmaxf(sqrtf(xn2[g]), 1e-15f);
            float u     = fminf(xnorm, 1.f - 1e-7f);
            float at    = 0.5f * __logf((1.f + u) / (1.f - u));   // artanh
            float Mxn   = fmaxf(sqrtf(m2), 1e-15f);
            float arg   = Mxn / xnorm * at;                        // >= 0
            float e     = __expf(2.f * arg);
            float th    = 1.f - 2.f / (e + 1.f);                   // tanh
            float scale = (Mxn <= 1e-10f) ? 0.f : th / Mxn;
            float y2 = scale * scale * m2;                         // ||y||^2
            float yb = scale * mbv;                                // y.b
            float t1  = 1.f + 2.f * yb + b2;
            float den = fmaxf(fmaf(y2, b2, 1.f + 2.f * yb), 1e-15f);
            float Af = t1 * scale / den;        // z = Af*Mx + Bf*bias
            float Bf = (1.f - y2) / den;
            float zn2 = Af * Af * m2 + 2.f * Af * Bf * mbv + Bf * Bf * b2;
            float zn  = fmaxf(sqrtf(zn2), 1e-15f);
            const float maxn = 1.f - 1e-5f;
            float fac = (zn > maxn) ? (maxn / zn) : 1.f;
            Af *= fac; Bf *= fac;

            float* orow = Out + (size_t)(rowbase + g * 16 + c) * 128;
#pragma unroll
            for (int n = 0; n < 8; ++n) {
                floatx4 o;
#pragma unroll
                for (int r = 0; r < 4; ++r)
                    o[r] = fmaf(Af, acc[g][n][r], Bf * bfr[n][r]);
                __builtin_nontemporal_store(o, reinterpret_cast<floatx4*>(orow + n * 16 + q * 4));
            }
        }
    }
}

extern "C" void kernel_launch(void* const* d_in, const int* in_sizes, int n_in,
                              void* d_out, int out_size, void* d_ws, size_t ws_size,
                              hipStream_t stream) {
    const float* X    = (const float*)d_in[0];
    const float* W    = (const float*)d_in[1];
    const float* Bias = (const float*)d_in[2];
    float* Out = (float*)d_out;

    dim3 grid(GRID), block(256);
    hipLaunchKernelGGL(mobius_linear_kernel, grid, block, 0, stream, X, W, Bias, Out);
}